// Round 19
// baseline (43.062 us; speedup 1.0000x reference)
//
#include <hip/hip_runtime.h>
#include <stdint.h>

#define NB 524288
#define NC 32
#define EPSV 1e-4f
#define DTB 0.12f      // DT * BETA
#define CLAMPV 3.0f
#define NSTEPS 4

typedef float f32x16 __attribute__((ext_vector_type(16)));
typedef float f32x2  __attribute__((ext_vector_type(2)));
typedef short short8 __attribute__((ext_vector_type(8)));

union FragU { uint32_t u[4]; short8 s; uint4 q; };

__device__ __forceinline__ uint32_t pkbf16(float a, float b) {
    uint32_t r;
    asm("v_cvt_pk_bf16_f32 %0, %1, %2" : "=v"(r) : "v"(a), "v"(b));
    return r;   // low16 = bf16(a), high16 = bf16(b)
}
__device__ __forceinline__ float lo16f(uint32_t w) { return __uint_as_float(w << 16); }
__device__ __forceinline__ float hi16f(uint32_t w) { return __uint_as_float(w & 0xffff0000u); }

// lane^32 exchange via v_permlane32_swap (VALU, ~8cyc) instead of ds_bpermute (~100cyc).
// With a=b=v: after swap a = lo-half broadcast, b = hi-half broadcast (per index);
// partner value = hi ? a : b. Pure data movement -> bit-exact.
__device__ __forceinline__ float sx32p(float v, int hi) {
    uint32_t a = __float_as_uint(v), b = a;
    asm("v_permlane32_swap_b32 %0, %1" : "+v"(a), "+v"(b));
    return hi ? __uint_as_float(a) : __uint_as_float(b);
}

// ws layout:
//  uint4 [0..63]    A1_hi : rows=centers, k<8: -2c/mu^2, k=8: (|c|^2+eps)/mu^2, k>=9: 0
//  uint4 [64..127]  A1_lo
//  uint4 [128..191] A2_hi chunk0 : rows 0..7 = c_d/mu^2, row 8 = 1/mu^2; k-axis PERMUTED:
//                   center(ch,k) = ch*16 + (k&3) + 8*((k>>2)&1) + 4*(k>>3)
//  uint4 [192..255] A2_hi chunk1
//  uint4 [256..319] A2_lo chunk0
//  uint4 [320..383] A2_lo chunk1
//  float [1536..1567] imtab: imtab[h*16+r] = 1/mu^2 of center crow(r,h)=(r&3)+8*(r>>2)+4*h
__global__ void prep_kernel(const float* __restrict__ centers,
                            const float* __restrict__ mus,
                            uint4* __restrict__ wsu) {
    int t = threadIdx.x;
    if (t >= 64) return;
    int row = t & 31, part = t >> 5;

    float mu = mus[row];
    float im2 = 1.0f / (mu * mu);
    float c[8];
    float bb = EPSV;
    #pragma unroll
    for (int d = 0; d < 8; ++d) { c[d] = centers[row * 8 + d]; bb = fmaf(c[d], c[d], bb); }
    float v[8];
    #pragma unroll
    for (int i = 0; i < 8; ++i) {
        int k = part * 8 + i;
        v[i] = (k < 8) ? (-2.0f * c[k] * im2) : (k == 8) ? (bb * im2) : 0.0f;
    }
    uint32_t h[4], l[4];
    #pragma unroll
    for (int j = 0; j < 4; ++j) {
        float a = v[2 * j], b = v[2 * j + 1];
        h[j] = pkbf16(a, b);
        l[j] = pkbf16(a - lo16f(h[j]), b - hi16f(h[j]));
    }
    wsu[t]      = make_uint4(h[0], h[1], h[2], h[3]);
    wsu[64 + t] = make_uint4(l[0], l[1], l[2], l[3]);

    #pragma unroll
    for (int ch = 0; ch < 2; ++ch) {
        float v2[8];
        #pragma unroll
        for (int i = 0; i < 8; ++i) {
            int k = part * 8 + i;
            int within = (k & 3) + 8 * ((k >> 2) & 1) + 4 * (k >> 3);
            int ci = ch * 16 + within;
            float muc = mus[ci];
            float im2c = 1.0f / (muc * muc);
            v2[i] = (row < 8) ? (centers[ci * 8 + row] * im2c) : (row == 8) ? im2c : 0.0f;
        }
        uint32_t h2[4], l2[4];
        #pragma unroll
        for (int j = 0; j < 4; ++j) {
            float a = v2[2 * j], b = v2[2 * j + 1];
            h2[j] = pkbf16(a, b);
            l2[j] = pkbf16(a - lo16f(h2[j]), b - hi16f(h2[j]));
        }
        wsu[128 + ch * 64 + t] = make_uint4(h2[0], h2[1], h2[2], h2[3]);
        wsu[256 + ch * 64 + t] = make_uint4(l2[0], l2[1], l2[2], l2[3]);
    }

    if (t < 32) {
        int h2i = t >> 4, r = t & 15;
        int ci = (r & 3) + 8 * (r >> 2) + 4 * h2i;
        float muc = mus[ci];
        ((float*)wsu)[1536 + t] = 1.0f / (muc * muc);
    }
}

__global__ __launch_bounds__(256, 4) void pm_kernel(
    const float* __restrict__ z_in,
    const uint4* __restrict__ wsu,
    float* __restrict__ out)
{
    const int tid  = threadIdx.x;
    const int wid  = tid >> 6;
    const int lane = tid & 63;
    const int hi   = lane >> 5;          // half-wave id
    const int col  = lane & 31;          // point within tile
    const int point = blockIdx.x * 128 + wid * 32 + col;

    // constant fragments (L2-resident)
    FragU A1h, A1l, A2h0, A2h1, A2l0, A2l1;
    A1h.q  = wsu[lane];        A1l.q  = wsu[64 + lane];
    A2h0.q = wsu[128 + lane];  A2h1.q = wsu[192 + lane];
    A2l0.q = wsu[256 + lane];  A2l1.q = wsu[320 + lane];

    // per-lane fp32 constants: imv[r] = 1/mu^2 of center crow(r,hi)
    const float* imt = ((const float*)wsu) + 1536 + hi * 16;
    float imv[16];
    #pragma unroll
    for (int r = 0; r < 16; ++r) imv[r] = imt[r];

    // z: this lane owns dims [hi*4 .. hi*4+3] (za); partner half via permlane (zb)
    const float4* zp4 = (const float4*)z_in;
    float4 hvec = zp4[(size_t)point * 2 + hi];
    float za0 = hvec.x, za1 = hvec.y, za2 = hvec.z, za3 = hvec.w;
    float zb0 = sx32p(za0, hi), zb1 = sx32p(za1, hi);
    float zb2 = sx32p(za2, hi), zb3 = sx32p(za3, hi);

    #pragma unroll 1
    for (int s = 0; s < NSTEPS; ++s) {
        // zz = |z|^2 (fp32, stays OUT of the bf16 GEMM)
        float zz = za0 * za0;
        zz = fmaf(za1, za1, zz); zz = fmaf(za2, za2, zz); zz = fmaf(za3, za3, zz);
        zz = fmaf(zb0, zb0, zz); zz = fmaf(zb1, zb1, zz);
        zz = fmaf(zb2, zb2, zz); zz = fmaf(zb3, zb3, zz);

        // ---- B1 (z_ext, col = point): hi0 lanes carry z dims 0..7; hi1 carry [1,0,...] ----
        uint32_t w0 = pkbf16(za0, za1), w1 = pkbf16(za2, za3);
        uint32_t w2 = pkbf16(zb0, zb1), w3w = pkbf16(zb2, zb3);
        uint32_t q0 = pkbf16(1.0f, 0.0f);   // k=8: exact 1; k=9: 0
        uint32_t w0l = pkbf16(za0 - lo16f(w0), za1 - hi16f(w0));
        uint32_t w1l = pkbf16(za2 - lo16f(w1), za3 - hi16f(w1));
        uint32_t w2l = pkbf16(zb0 - lo16f(w2), zb1 - hi16f(w2));
        uint32_t w3l = pkbf16(zb2 - lo16f(w3w), zb3 - hi16f(w3w));

        FragU B1h, B1l;
        B1h.u[0] = hi ? q0 : w0;   B1h.u[1] = hi ? 0u : w1;
        B1h.u[2] = hi ? 0u : w2;   B1h.u[3] = hi ? 0u : w3w;
        B1l.u[0] = hi ? 0u : w0l;  B1l.u[1] = hi ? 0u : w1l;
        B1l.u[2] = hi ? 0u : w2l;  B1l.u[3] = hi ? 0u : w3l;

        // ---- GEMM1: D1[center][point] = (bb - 2 z.c)/mu^2, full 4-term split (r14-exact) ----
        __builtin_amdgcn_s_setprio(1);
        f32x16 D1 = {};
        D1 = __builtin_amdgcn_mfma_f32_32x32x16_bf16(A1h.s, B1h.s, D1, 0, 0, 0);
        D1 = __builtin_amdgcn_mfma_f32_32x32x16_bf16(A1h.s, B1l.s, D1, 0, 0, 0);
        D1 = __builtin_amdgcn_mfma_f32_32x32x16_bf16(A1l.s, B1h.s, D1, 0, 0, 0);
        D1 = __builtin_amdgcn_mfma_f32_32x32x16_bf16(A1l.s, B1l.s, D1, 0, 0, 0);
        __builtin_amdgcn_s_setprio(0);

        // ---- elementwise: r2' = D1 + zz/mu^2 (fp32) ; w = rsq(r2') = mu/r ----
        float wv[16];
        #pragma unroll
        for (int r = 0; r < 16; ++r) {
            float r2 = fmaf(zz, imv[r], D1[r]);
            wv[r] = __builtin_amdgcn_rsqf(r2);
        }
        float t0 = wv[0] + wv[1],   t1 = wv[2] + wv[3],   t2 = wv[4] + wv[5],   t3 = wv[6] + wv[7];
        float t4 = wv[8] + wv[9],   t5 = wv[10] + wv[11], t6 = wv[12] + wv[13], t7 = wv[14] + wv[15];
        float n_half = ((t0 + t1) + (t2 + t3)) + ((t4 + t5) + (t6 + t7));

        // w^3 packed (v_pk_mul_f32: same IEEE mul per element, bit-exact)
        f32x2 w3p[8];
        #pragma unroll
        for (int j = 0; j < 8; ++j) {
            f32x2 wp = {wv[2 * j], wv[2 * j + 1]};
            w3p[j] = (wp * wp) * wp;
        }

        // ---- B2 pack: pure local, WITH lo-residual (r14-exact) ----
        FragU B2c0h, B2c1h, B2c0l, B2c1l;
        #pragma unroll
        for (int j = 0; j < 4; ++j) {
            float a = w3p[j].x, b = w3p[j].y;
            uint32_t ph = pkbf16(a, b);
            B2c0h.u[j] = ph;
            B2c0l.u[j] = pkbf16(a - lo16f(ph), b - hi16f(ph));
        }
        #pragma unroll
        for (int j = 0; j < 4; ++j) {
            float a = w3p[4 + j].x, b = w3p[4 + j].y;
            uint32_t ph = pkbf16(a, b);
            B2c1h.u[j] = ph;
            B2c1l.u[j] = pkbf16(a - lo16f(ph), b - hi16f(ph));
        }

        // ---- GEMM2: 8-term split (r14-exact) ----
        __builtin_amdgcn_s_setprio(1);
        f32x16 D2 = {};
        D2 = __builtin_amdgcn_mfma_f32_32x32x16_bf16(A2h0.s, B2c0h.s, D2, 0, 0, 0);
        D2 = __builtin_amdgcn_mfma_f32_32x32x16_bf16(A2h1.s, B2c1h.s, D2, 0, 0, 0);
        D2 = __builtin_amdgcn_mfma_f32_32x32x16_bf16(A2l0.s, B2c0h.s, D2, 0, 0, 0);
        D2 = __builtin_amdgcn_mfma_f32_32x32x16_bf16(A2l1.s, B2c1h.s, D2, 0, 0, 0);
        D2 = __builtin_amdgcn_mfma_f32_32x32x16_bf16(A2h0.s, B2c0l.s, D2, 0, 0, 0);
        D2 = __builtin_amdgcn_mfma_f32_32x32x16_bf16(A2h1.s, B2c1l.s, D2, 0, 0, 0);
        D2 = __builtin_amdgcn_mfma_f32_32x32x16_bf16(A2l0.s, B2c0l.s, D2, 0, 0, 0);
        D2 = __builtin_amdgcn_mfma_f32_32x32x16_bf16(A2l1.s, B2c1l.s, D2, 0, 0, 0);
        __builtin_amdgcn_s_setprio(0);

        // ---- epilogue (packed; v_pk_fma/min/max bit-exact per element) ----
        float n  = 1.0f + n_half + sx32p(n_half, hi);
        float swp = D2[4];                    // hi0: row8 = sw ; hi1: row12 = 0
        float sw = swp + sx32p(swp, hi);
        float scale = DTB * __builtin_amdgcn_rcpf(n);

        f32x2 nsw = {-sw, -sw}, scl = {scale, scale};
        const f32x2 lo = {-CLAMPV, -CLAMPV}, hicl = {CLAMPV, CLAMPV};
        f32x2 za01 = {za0, za1}, za23 = {za2, za3};
        f32x2 d01  = {D2[0], D2[1]}, d23 = {D2[2], D2[3]};
        f32x2 g01 = __builtin_elementwise_fma(nsw, za01, d01);
        f32x2 g23 = __builtin_elementwise_fma(nsw, za23, d23);
        f32x2 zn01 = __builtin_elementwise_fma(scl, g01, za01);
        f32x2 zn23 = __builtin_elementwise_fma(scl, g23, za23);
        zn01 = __builtin_elementwise_min(__builtin_elementwise_max(zn01, lo), hicl);
        zn23 = __builtin_elementwise_min(__builtin_elementwise_max(zn23, lo), hicl);
        za0 = zn01.x; za1 = zn01.y; za2 = zn23.x; za3 = zn23.y;
        zb0 = sx32p(za0, hi); zb1 = sx32p(za1, hi);
        zb2 = sx32p(za2, hi); zb3 = sx32p(za3, hi);
    }

    float4* op = (float4*)out;
    op[(size_t)point * 2 + hi] = make_float4(za0, za1, za2, za3);
}

extern "C" void kernel_launch(void* const* d_in, const int* in_sizes, int n_in,
                              void* d_out, int out_size, void* d_ws, size_t ws_size,
                              hipStream_t stream) {
    const float* z       = (const float*)d_in[0];
    const float* centers = (const float*)d_in[1];
    const float* mus     = (const float*)d_in[2];
    float* out           = (float*)d_out;
    uint4* wsu           = (uint4*)d_ws;

    prep_kernel<<<1, 64, 0, stream>>>(centers, mus, wsu);
    pm_kernel<<<NB / 128, 256, 0, stream>>>(z, wsu, out);   // 4096 blocks, 32 pts/wave
}

// Round 20
// 38.451 us; speedup vs baseline: 1.1199x; 1.1199x over previous
//
#include <hip/hip_runtime.h>
#include <stdint.h>

#define NB 524288
#define NC 32
#define EPSV 1e-4f
#define DTB 0.12f      // DT * BETA
#define CLAMPV 3.0f
#define NSTEPS 4

typedef float f32x16 __attribute__((ext_vector_type(16)));
typedef short short8 __attribute__((ext_vector_type(8)));

union FragU { uint32_t u[4]; short8 s; uint4 q; };

__device__ __forceinline__ uint32_t pkbf16(float a, float b) {
    uint32_t r;
    asm("v_cvt_pk_bf16_f32 %0, %1, %2" : "=v"(r) : "v"(a), "v"(b));
    return r;   // low16 = bf16(a), high16 = bf16(b)
}
__device__ __forceinline__ float lo16f(uint32_t w) { return __uint_as_float(w << 16); }
__device__ __forceinline__ float hi16f(uint32_t w) { return __uint_as_float(w & 0xffff0000u); }
__device__ __forceinline__ float sx32(float v) { return __shfl_xor(v, 32); }

// ws layout:
//  uint4 [0..63]    A1_hi : rows=centers, k<8: -2c/mu^2, k=8: (|c|^2+eps)/mu^2, k>=9: 0
//  uint4 [64..127]  A1_lo
//  uint4 [128..191] A2_hi chunk0 : rows 0..7 = c_d/mu^2, row 8 = 1/mu^2; k-axis PERMUTED:
//                   center(ch,k) = ch*16 + (k&3) + 8*((k>>2)&1) + 4*(k>>3)
//  uint4 [192..255] A2_hi chunk1
//  uint4 [256..319] A2_lo chunk0
//  uint4 [320..383] A2_lo chunk1
//  float [1536..1567] imtab: imtab[h*16+r] = 1/mu^2 of center crow(r,h)=(r&3)+8*(r>>2)+4*h
__global__ void prep_kernel(const float* __restrict__ centers,
                            const float* __restrict__ mus,
                            uint4* __restrict__ wsu) {
    int t = threadIdx.x;
    if (t >= 64) return;
    int row = t & 31, part = t >> 5;

    float mu = mus[row];
    float im2 = 1.0f / (mu * mu);
    float c[8];
    float bb = EPSV;
    #pragma unroll
    for (int d = 0; d < 8; ++d) { c[d] = centers[row * 8 + d]; bb = fmaf(c[d], c[d], bb); }
    float v[8];
    #pragma unroll
    for (int i = 0; i < 8; ++i) {
        int k = part * 8 + i;
        v[i] = (k < 8) ? (-2.0f * c[k] * im2) : (k == 8) ? (bb * im2) : 0.0f;
    }
    uint32_t h[4], l[4];
    #pragma unroll
    for (int j = 0; j < 4; ++j) {
        float a = v[2 * j], b = v[2 * j + 1];
        h[j] = pkbf16(a, b);
        l[j] = pkbf16(a - lo16f(h[j]), b - hi16f(h[j]));
    }
    wsu[t]      = make_uint4(h[0], h[1], h[2], h[3]);
    wsu[64 + t] = make_uint4(l[0], l[1], l[2], l[3]);

    #pragma unroll
    for (int ch = 0; ch < 2; ++ch) {
        float v2[8];
        #pragma unroll
        for (int i = 0; i < 8; ++i) {
            int k = part * 8 + i;
            int within = (k & 3) + 8 * ((k >> 2) & 1) + 4 * (k >> 3);
            int ci = ch * 16 + within;
            float muc = mus[ci];
            float im2c = 1.0f / (muc * muc);
            v2[i] = (row < 8) ? (centers[ci * 8 + row] * im2c) : (row == 8) ? im2c : 0.0f;
        }
        uint32_t h2[4], l2[4];
        #pragma unroll
        for (int j = 0; j < 4; ++j) {
            float a = v2[2 * j], b = v2[2 * j + 1];
            h2[j] = pkbf16(a, b);
            l2[j] = pkbf16(a - lo16f(h2[j]), b - hi16f(h2[j]));
        }
        wsu[128 + ch * 64 + t] = make_uint4(h2[0], h2[1], h2[2], h2[3]);
        wsu[256 + ch * 64 + t] = make_uint4(l2[0], l2[1], l2[2], l2[3]);
    }

    if (t < 32) {
        int h2i = t >> 4, r = t & 15;
        int ci = (r & 3) + 8 * (r >> 2) + 4 * h2i;
        float muc = mus[ci];
        ((float*)wsu)[1536 + t] = 1.0f / (muc * muc);
    }
}

__global__ __launch_bounds__(256, 4) void pm_kernel(
    const float* __restrict__ z_in,
    const uint4* __restrict__ wsu,
    float* __restrict__ out)
{
    const int tid  = threadIdx.x;
    const int wid  = tid >> 6;
    const int lane = tid & 63;
    const int hi   = lane >> 5;          // half-wave id
    const int col  = lane & 31;          // point within tile
    const int point = blockIdx.x * 128 + wid * 32 + col;

    // constant fragments (L2-resident)
    FragU A1h, A1l, A2h0, A2h1, A2l0, A2l1;
    A1h.q  = wsu[lane];        A1l.q  = wsu[64 + lane];
    A2h0.q = wsu[128 + lane];  A2h1.q = wsu[192 + lane];
    A2l0.q = wsu[256 + lane];  A2l1.q = wsu[320 + lane];

    // per-lane fp32 constants: imv[r] = 1/mu^2 of center crow(r,hi)
    const float* imt = ((const float*)wsu) + 1536 + hi * 16;
    float imv[16];
    #pragma unroll
    for (int r = 0; r < 16; ++r) imv[r] = imt[r];

    // z: this lane owns dims [hi*4 .. hi*4+3] (za); partner half via shfl (zb)
    const float4* zp4 = (const float4*)z_in;
    float4 hvec = zp4[(size_t)point * 2 + hi];
    float za0 = hvec.x, za1 = hvec.y, za2 = hvec.z, za3 = hvec.w;
    float zb0 = sx32(za0), zb1 = sx32(za1), zb2 = sx32(za2), zb3 = sx32(za3);

    #pragma unroll
    for (int s = 0; s < NSTEPS; ++s) {
        // zz = |z|^2 (fp32, stays OUT of the bf16 GEMM)
        float zz = za0 * za0;
        zz = fmaf(za1, za1, zz); zz = fmaf(za2, za2, zz); zz = fmaf(za3, za3, zz);
        zz = fmaf(zb0, zb0, zz); zz = fmaf(zb1, zb1, zz);
        zz = fmaf(zb2, zb2, zz); zz = fmaf(zb3, zb3, zz);

        // ---- B1 (z_ext, col = point): hi0 lanes carry z dims 0..7; hi1 carry [1,0,...] ----
        uint32_t w0 = pkbf16(za0, za1), w1 = pkbf16(za2, za3);
        uint32_t w2 = pkbf16(zb0, zb1), w3w = pkbf16(zb2, zb3);
        uint32_t q0 = pkbf16(1.0f, 0.0f);   // k=8: exact 1; k=9: 0
        uint32_t w0l = pkbf16(za0 - lo16f(w0), za1 - hi16f(w0));
        uint32_t w1l = pkbf16(za2 - lo16f(w1), za3 - hi16f(w1));
        uint32_t w2l = pkbf16(zb0 - lo16f(w2), zb1 - hi16f(w2));
        uint32_t w3l = pkbf16(zb2 - lo16f(w3w), zb3 - hi16f(w3w));

        FragU B1h, B1l;
        B1h.u[0] = hi ? q0 : w0;   B1h.u[1] = hi ? 0u : w1;
        B1h.u[2] = hi ? 0u : w2;   B1h.u[3] = hi ? 0u : w3w;
        B1l.u[0] = hi ? 0u : w0l;  B1l.u[1] = hi ? 0u : w1l;
        B1l.u[2] = hi ? 0u : w2l;  B1l.u[3] = hi ? 0u : w3l;

        // ---- GEMM1: D1[center][point] = (bb - 2 z.c)/mu^2, full 4-term split (r14-exact) ----
        f32x16 D1 = {};
        D1 = __builtin_amdgcn_mfma_f32_32x32x16_bf16(A1h.s, B1h.s, D1, 0, 0, 0);
        D1 = __builtin_amdgcn_mfma_f32_32x32x16_bf16(A1h.s, B1l.s, D1, 0, 0, 0);
        D1 = __builtin_amdgcn_mfma_f32_32x32x16_bf16(A1l.s, B1h.s, D1, 0, 0, 0);
        D1 = __builtin_amdgcn_mfma_f32_32x32x16_bf16(A1l.s, B1l.s, D1, 0, 0, 0);

        // ---- elementwise: r2' = D1 + zz/mu^2 (fp32) ; w = rsq(r2') = mu/r ----
        float wv[16];
        #pragma unroll
        for (int r = 0; r < 16; ++r) {
            float r2 = fmaf(zz, imv[r], D1[r]);
            wv[r] = __builtin_amdgcn_rsqf(r2);
        }
        float t0 = wv[0] + wv[1],   t1 = wv[2] + wv[3],   t2 = wv[4] + wv[5],   t3 = wv[6] + wv[7];
        float t4 = wv[8] + wv[9],   t5 = wv[10] + wv[11], t6 = wv[12] + wv[13], t7 = wv[14] + wv[15];
        float n_half = ((t0 + t1) + (t2 + t3)) + ((t4 + t5) + (t6 + t7));
        float w3v[16];
        #pragma unroll
        for (int r = 0; r < 16; ++r) w3v[r] = (wv[r] * wv[r]) * wv[r];

        // ---- B2 pack: pure local, WITH lo-residual (r14-exact) ----
        FragU B2c0h, B2c1h, B2c0l, B2c1l;
        #pragma unroll
        for (int j = 0; j < 4; ++j) {
            float a = w3v[2 * j], b = w3v[2 * j + 1];
            uint32_t ph = pkbf16(a, b);
            B2c0h.u[j] = ph;
            B2c0l.u[j] = pkbf16(a - lo16f(ph), b - hi16f(ph));
        }
        #pragma unroll
        for (int j = 0; j < 4; ++j) {
            float a = w3v[8 + 2 * j], b = w3v[8 + 2 * j + 1];
            uint32_t ph = pkbf16(a, b);
            B2c1h.u[j] = ph;
            B2c1l.u[j] = pkbf16(a - lo16f(ph), b - hi16f(ph));
        }

        // ---- GEMM2: 8-term split (r14-exact) ----
        f32x16 D2 = {};
        D2 = __builtin_amdgcn_mfma_f32_32x32x16_bf16(A2h0.s, B2c0h.s, D2, 0, 0, 0);
        D2 = __builtin_amdgcn_mfma_f32_32x32x16_bf16(A2h1.s, B2c1h.s, D2, 0, 0, 0);
        D2 = __builtin_amdgcn_mfma_f32_32x32x16_bf16(A2l0.s, B2c0h.s, D2, 0, 0, 0);
        D2 = __builtin_amdgcn_mfma_f32_32x32x16_bf16(A2l1.s, B2c1h.s, D2, 0, 0, 0);
        D2 = __builtin_amdgcn_mfma_f32_32x32x16_bf16(A2h0.s, B2c0l.s, D2, 0, 0, 0);
        D2 = __builtin_amdgcn_mfma_f32_32x32x16_bf16(A2h1.s, B2c1l.s, D2, 0, 0, 0);
        D2 = __builtin_amdgcn_mfma_f32_32x32x16_bf16(A2l0.s, B2c0l.s, D2, 0, 0, 0);
        D2 = __builtin_amdgcn_mfma_f32_32x32x16_bf16(A2l1.s, B2c1l.s, D2, 0, 0, 0);

        // ---- epilogue ----
        float n  = 1.0f + n_half + sx32(n_half);
        float swp = D2[4];                    // hi0: row8 = sw ; hi1: row12 = 0
        float sw = swp + sx32(swp);
        float scale = DTB * __builtin_amdgcn_rcpf(n);

        float g0 = fmaf(-sw, za0, D2[0]);
        float g1 = fmaf(-sw, za1, D2[1]);
        float g2 = fmaf(-sw, za2, D2[2]);
        float g3 = fmaf(-sw, za3, D2[3]);
        za0 = fminf(fmaxf(fmaf(scale, g0, za0), -CLAMPV), CLAMPV);
        za1 = fminf(fmaxf(fmaf(scale, g1, za1), -CLAMPV), CLAMPV);
        za2 = fminf(fmaxf(fmaf(scale, g2, za2), -CLAMPV), CLAMPV);
        za3 = fminf(fmaxf(fmaf(scale, g3, za3), -CLAMPV), CLAMPV);
        zb0 = sx32(za0); zb1 = sx32(za1); zb2 = sx32(za2); zb3 = sx32(za3);
    }

    float4* op = (float4*)out;
    op[(size_t)point * 2 + hi] = make_float4(za0, za1, za2, za3);
}

extern "C" void kernel_launch(void* const* d_in, const int* in_sizes, int n_in,
                              void* d_out, int out_size, void* d_ws, size_t ws_size,
                              hipStream_t stream) {
    const float* z       = (const float*)d_in[0];
    const float* centers = (const float*)d_in[1];
    const float* mus     = (const float*)d_in[2];
    float* out           = (float*)d_out;
    uint4* wsu           = (uint4*)d_ws;

    prep_kernel<<<1, 64, 0, stream>>>(centers, mus, wsu);
    pm_kernel<<<NB / 128, 256, 0, stream>>>(z, wsu, out);   // 4096 blocks, 32 pts/wave
}